// Round 15
// baseline (165.262 us; speedup 1.0000x reference)
//
#include <hip/hip_runtime.h>

// CINLayer: cin_out[b,f,d] = sum_{c,n} W[f,c,n] * xj[b,c,d] * x0[b,n,d]
//           cin_p_out[b,f] = sum_d cin_out[b,f,d]
// B=2048, C=64, N=64, D=64, F=128.
//
// R15: wave reshaped to mf=2 x nf=2 (1 batch x 64 f per wave): each A'
// fragment (scale8a) feeds TWO MFMAs -> formation VALU per MFMA halves
// (the 1:1 ratio was constant across all prior rounds). W single-buffered
// in regs with in-cluster dead-reload (R14's spreading); xj prefetched at
// cluster top (full-phase LDS latency cover). No setprio. 3 waves/SIMD.

typedef _Float16 f16;
typedef __attribute__((ext_vector_type(8))) _Float16 half8;
typedef __attribute__((ext_vector_type(16))) float f32x16;
typedef __attribute__((ext_vector_type(4))) float f32x4;

#define MFMA(a, b, c) __builtin_amdgcn_mfma_f32_32x32x16_f16(a, b, c, 0, 0, 0)

union U8 { half8 v; unsigned u[4]; };

__device__ __forceinline__ half8 scale8a(half8 a, unsigned hdup) {
  U8 in, out;
  in.v = a;
  asm("v_pk_mul_f16 %0, %1, %2" : "=v"(out.u[0]) : "v"(in.u[0]), "v"(hdup));
  asm("v_pk_mul_f16 %0, %1, %2" : "=v"(out.u[1]) : "v"(in.u[1]), "v"(hdup));
  asm("v_pk_mul_f16 %0, %1, %2" : "=v"(out.u[2]) : "v"(in.u[2]), "v"(hdup));
  asm("v_pk_mul_f16 %0, %1, %2" : "=v"(out.u[3]) : "v"(in.u[3]), "v"(hdup));
  return out.v;
}

__device__ __forceinline__ unsigned dup16(float f) {
  f16 h = (f16)f;
  union { f16 h; unsigned short s; } u; u.h = h;
  return (unsigned)u.s * 0x10001u;
}

// ---- pre-pass: scatter W f32 -> f16 fragment-major ----
// Wb slot layout: [c][slot][8], slot = (g*4+kk)*64 + lane (lane=hi*32+lr)
//   holds W[f=g*32+lr][c][kk*16+hi*8 .. +8]
__global__ __launch_bounds__(256) void wscat_kernel(const float* __restrict__ W,
                                                    f16* __restrict__ Wb) {
  const int tid = blockIdx.x * 256 + threadIdx.x;   // 65536 threads
  const int c = tid >> 10, s = tid & 1023;
  const int gk = s >> 6, ln = s & 63;
  const int g = gk >> 2, kk = gk & 3, hi = ln >> 5, lr = ln & 31;
  const int f = g * 32 + lr, n0 = kk * 16 + hi * 8;
  const float* src = W + (size_t)f * 4096 + c * 64 + n0;
  const float4 a = *(const float4*)src;
  const float4 b = *(const float4*)(src + 4);
  half8 r;
  r[0] = (f16)a.x; r[1] = (f16)a.y; r[2] = (f16)a.z; r[3] = (f16)a.w;
  r[4] = (f16)b.x; r[5] = (f16)b.y; r[6] = (f16)b.z; r[7] = (f16)b.w;
  *(half8*)(Wb + (size_t)c * 8192 + s * 8) = r;
}

__global__ __launch_bounds__(256, 2) void cin_kernel(
    const float* __restrict__ xj, const float* __restrict__ x0,
    const f16* __restrict__ Wb, float* __restrict__ out,
    float* __restrict__ pout) {
  // x0T[bb*4096 + d*64 + ((n>>3)^(d&7))*8 + (n&7)] = f16(x0[b0+bb][n][d])
  __shared__ f16 x0T[2 * 4096];        // 16 KB
  // xjD[bb*4096 + c*64 + d] = dup16(xj[b0+bb][c][d])  (u32 broadcast pairs)
  __shared__ unsigned xjD[2 * 4096];   // 32 KB

  const int t = threadIdx.x;
  const int wid = t >> 6, lane = t & 63;
  const int b0 = blockIdx.x * 2;

  // ---- one-time: stage x0 (transposed, swizzled) + xj (dup-u32) ----
#pragma unroll
  for (int bb = 0; bb < 2; ++bb) {
    const float* s0 = x0 + (size_t)(b0 + bb) * 4096;
    const float* sj = xj + (size_t)(b0 + bb) * 4096;
    {
      const int n = lane, d0 = wid * 16;
      const int chb = n >> 3, sub = n & 7;
#pragma unroll
      for (int q = 0; q < 4; ++q) {
        const float4 v = *(const float4*)(s0 + n * 64 + d0 + q * 4);
#pragma unroll
        for (int j = 0; j < 4; ++j) {
          const int d = d0 + q * 4 + j;
          x0T[bb * 4096 + d * 64 + ((chb ^ (d & 7)) << 3) + sub] =
              (f16)(((const float*)&v)[j]);
        }
      }
    }
#pragma unroll
    for (int p = 0; p < 4; ++p) {
      const int e = p * 1024 + t * 4;
      const float4 v = *(const float4*)(sj + e);
      unsigned* dst = &xjD[bb * 4096 + e];
      dst[0] = dup16(v.x); dst[1] = dup16(v.y);
      dst[2] = dup16(v.z); dst[3] = dup16(v.w);
    }
  }
  __syncthreads();

  // wave: bb = batch, fh = f-half (f = fh*64 + nf*32 + lr)
  const int bb = wid >> 1, fh = wid & 1;
  const int lr = lane & 31, hi = lane >> 5;

  // ---- hoisted x0 A-fragments: af[mf][kk], d = mf*32 + lr, batch bb ----
  half8 af[2][4];
#pragma unroll
  for (int mf = 0; mf < 2; ++mf) {
    const int d = mf * 32 + lr;
#pragma unroll
    for (int kk = 0; kk < 4; ++kk)
      af[mf][kk] = *(const half8*)&x0T[bb * 4096 + d * 64 +
                                       (((kk * 2 + hi) ^ (d & 7)) << 3)];
  }

  f32x16 acc00 = {}, acc01 = {}, acc10 = {}, acc11 = {};

  // W stream (half8 units): c*1024 + (fh*2+nf)*256 + kk*64 + lane
  const half8* wp = (const half8*)Wb + fh * 512 + lane;

  // ---- prologue: W(c=0) -> single-buffer regs; xj(c=0) ----
  half8 w00 = wp[0],   w01 = wp[64],  w02 = wp[128], w03 = wp[192];
  half8 w10 = wp[256], w11 = wp[320], w12 = wp[384], w13 = wp[448];
  const half8* wpn = wp + 1024;                 // reload target: c+1

  const unsigned* xjp = &xjD[bb * 4096 + lr];
  unsigned x0v = xjp[0], x1v = xjp[32];
  const unsigned* xjpn = xjp + 64;              // prefetch target: c+1

#pragma unroll 1
  for (int c = 0; c < 63; ++c) {
    // prefetch next xj at cluster top (full-phase LDS latency cover)
    const unsigned xn0 = xjpn[0], xn1 = xjpn[32];

    // ---- kk = 0 ----
    half8 a0 = scale8a(af[0][0], x0v);
    half8 a1 = scale8a(af[1][0], x1v);
    acc00 = MFMA(a0, w00, acc00);
    acc10 = MFMA(a1, w00, acc10);
    w00 = wpn[0];                               // dead -> reload c+1
    acc01 = MFMA(a0, w10, acc01);
    acc11 = MFMA(a1, w10, acc11);
    w10 = wpn[256];
    // ---- kk = 1 ----
    a0 = scale8a(af[0][1], x0v);
    a1 = scale8a(af[1][1], x1v);
    acc00 = MFMA(a0, w01, acc00);
    acc10 = MFMA(a1, w01, acc10);
    w01 = wpn[64];
    acc01 = MFMA(a0, w11, acc01);
    acc11 = MFMA(a1, w11, acc11);
    w11 = wpn[320];
    // ---- kk = 2 ----
    a0 = scale8a(af[0][2], x0v);
    a1 = scale8a(af[1][2], x1v);
    acc00 = MFMA(a0, w02, acc00);
    acc10 = MFMA(a1, w02, acc10);
    w02 = wpn[128];
    acc01 = MFMA(a0, w12, acc01);
    acc11 = MFMA(a1, w12, acc11);
    w12 = wpn[384];
    // ---- kk = 3 ----
    a0 = scale8a(af[0][3], x0v);
    a1 = scale8a(af[1][3], x1v);
    acc00 = MFMA(a0, w03, acc00);
    acc10 = MFMA(a1, w03, acc10);
    w03 = wpn[192];
    acc01 = MFMA(a0, w13, acc01);
    acc11 = MFMA(a1, w13, acc11);
    w13 = wpn[448];

    x0v = xn0; x1v = xn1;
    wpn += 1024; xjpn += 64;
  }

  // ---- peeled last phase c=63: no reloads ----
#pragma unroll
  for (int kk = 0; kk < 4; ++kk) {
    const half8 a0 = scale8a(af[0][kk], x0v);
    const half8 a1 = scale8a(af[1][kk], x1v);
    const half8 wl = (kk == 0) ? w00 : (kk == 1) ? w01 : (kk == 2) ? w02 : w03;
    const half8 wh = (kk == 0) ? w10 : (kk == 1) ? w11 : (kk == 2) ? w12 : w13;
    acc00 = MFMA(a0, wl, acc00);
    acc10 = MFMA(a1, wl, acc10);
    acc01 = MFMA(a0, wh, acc01);
    acc11 = MFMA(a1, wh, acc11);
  }

  // ---- epilogue: D layout col=lane&31 (f), row=(reg&3)+8*(reg>>2)+4*hi (d) ----
  const int b = b0 + bb;
  float psum[2] = {0.f, 0.f};
#pragma unroll
  for (int nf = 0; nf < 2; ++nf) {
    const int fcol = fh * 64 + nf * 32 + lr;
    float* ob = out + (size_t)b * 8192 + (size_t)fcol * 64;
#pragma unroll
    for (int mf = 0; mf < 2; ++mf) {
      const f32x16 v = (nf == 0) ? ((mf == 0) ? acc00 : acc10)
                                 : ((mf == 0) ? acc01 : acc11);
      float s = 0.f;
#pragma unroll
      for (int q = 0; q < 4; ++q) {
        f32x4 vv = { v[4 * q], v[4 * q + 1], v[4 * q + 2], v[4 * q + 3] };
        *(f32x4*)(ob + mf * 32 + q * 8 + hi * 4) = vv;
        s += vv[0] + vv[1] + vv[2] + vv[3];
      }
      psum[nf] += s;
    }
  }
#pragma unroll
  for (int nf = 0; nf < 2; ++nf) {
    float s = psum[nf];
    s += __shfl_xor(s, 32, 64);
    if (hi == 0) pout[(size_t)b * 128 + fh * 64 + nf * 32 + lr] = s;
  }
}

extern "C" void kernel_launch(void* const* d_in, const int* in_sizes, int n_in,
                              void* d_out, int out_size, void* d_ws, size_t ws_size,
                              hipStream_t stream) {
  const float* xj = (const float*)d_in[0];   // (2048, 64, 64)
  const float* x0 = (const float*)d_in[1];   // (2048, 64, 64)
  const float* W  = (const float*)d_in[2];   // (128, 64, 64)
  float* out  = (float*)d_out;               // cin_out (2048,128,64), cin_p_out (2048,128)
  float* pout = out + (size_t)2048 * 128 * 64;
  f16* Wb = (f16*)d_ws;                      // 1 MiB fragment-major f16 W

  wscat_kernel<<<256, 256, 0, stream>>>(W, Wb);
  cin_kernel<<<1024, 256, 0, stream>>>(xj, x0, Wb, out, pout);
}